// Round 13
// baseline (117.711 us; speedup 1.0000x reference)
//
#include <hip/hip_runtime.h>
#include <math.h>

#define NQ 12
#define NTH 256
#define NL 3
#define GRID 512   // 2 blocks/CU; 4 waves/block, 1 sample/wave, 16 samples/block

typedef _Float16 h8 __attribute__((ext_vector_type(8)));
typedef _Float16 h4 __attribute__((ext_vector_type(4)));
typedef float f4 __attribute__((ext_vector_type(4)));

#define MFMA __builtin_amdgcn_mfma_f32_16x16x32_f16

// R27: wave-per-sample, BARRIER-FREE main loop. R19-R26 ledger: barriers
// -44%, VALU -15%, DS -40%, occupancy levers exhausted -- time pinned
// ~55us => the 4-wave lockstep itself (barrier-latency serialization) is
// the wall. Here ONE wave owns one sample and plays all 4 old wave-roles
// sequentially (wvx loop); every transition becomes wave-internal, ordered
// by compiler lgkmcnt. The scatter-vs-g1-read hazard is closed by staging
// all 16 g1 A-frags in registers before any scatter. 2 barriers total
// (setup); zero in the sample loop. 4 waves/block = 4 independent samples;
// Wl shared (built once per 16 samples). LDS 78KB -> 2 blocks/CU = 8
// independent wave-streams/CU. launch_bounds(256,2): VGPR cap 256
// non-binding (LDS caps residency) -> no spill by construction.
//
// Bit bookkeeping (state index i[11:0], wire w <-> bit 11-w):
//  L0 (LDS): off = i[11:4]*32 + reim*16 + i[3:0], swzf
//  g0 A: elem=i[2:0], q=(reim,i[3]), row u=(i[9:8],i[5:4]), mb=i[7:6], wvx=i[11:10]
//  L1 (LDS): off = m1*32 + reim*16 + i[7:4], m1=(i[11:10],i[9:8],i[3:0]), swz1
//  g1 A: elem=i[6:4], q=(reim,i[7]), row=i[11:8], mb=i[1:0], wvx=i[3:2]
//  in-reg transition -> g2 A: elem=i[10:8], q=(reim,i[11]), row=i[7:4], mb=i[1:0]
//  C(g2): col=i[11:8](lane3:0), l5:4=i[7:6], reg=i[5:4], mb=i[1:0], wvx=i[3:2]
//  CNOT scatter: dest j = sfx(i) (suffix parity), h4-contiguous in j[1:0]<->mb.

__device__ __forceinline__ int sfx(int v) {
    v ^= v >> 1; v ^= v >> 2; v ^= v >> 4; v ^= v >> 8;
    return v;
}
__device__ __forceinline__ int swzf(int off) {   // L0 swizzle (R6-verified)
    return off ^ (((((off >> 6) ^ (off >> 9)) & 7)) << 3);
}
__device__ __forceinline__ int swz1(int off) {   // L1 swizzle (rank-3 bank classes both sides)
    return off ^ ((((off >> 5) ^ (off >> 9)) & 7) << 3);
}
__device__ __forceinline__ int swzw(int off) {   // W-buffer swizzle (R7-verified)
    return off ^ (((off >> 6) & 7) << 3);
}

// f32 pair -> packed 2xf16 dword via v_cvt_pkrtz_f16_f32 (lo in low half)
__device__ __forceinline__ unsigned pk2(float lo, float hi) {
    auto t_ = __builtin_amdgcn_cvt_pkrtz(lo, hi);   // __fp16x2
    unsigned r_; __builtin_memcpy(&r_, &t_, 4); return r_;
}

// C(g1) fragment (4 re regs + 4 im regs) -> A(g2) h8 fragment, in-wave.
__device__ __forceinline__ h8 xition(f4 re, f4 im) {
    unsigned a0 = pk2(re.x, re.y), a1 = pk2(re.z, re.w);
    unsigned b0 = pk2(im.x, im.y), b1 = pk2(im.z, im.w);
    asm("v_permlane32_swap_b32 %0, %1" : "+v"(a0), "+v"(b0));
    asm("v_permlane16_swap_b32 %0, %1" : "+v"(a0), "+v"(b0));
    asm("v_permlane32_swap_b32 %0, %1" : "+v"(a1), "+v"(b1));
    asm("v_permlane16_swap_b32 %0, %1" : "+v"(a1), "+v"(b1));
    union { unsigned u[4]; h8 v; } r_;
    r_.u[0] = a0; r_.u[1] = a1; r_.u[2] = b0; r_.u[3] = b1;
    return r_.v;
}

__global__ void __launch_bounds__(NTH, 2)
qsim_kernel(const float* __restrict__ x,
            const float* __restrict__ params,
            const float* __restrict__ head_w,
            const float* __restrict__ head_b,
            float* __restrict__ out, int Btot) {
    __shared__ __align__(16) _Float16 Sst[4][8192];  // 64 KB: one sample per wave
    __shared__ __align__(16) _Float16 Wl[6144];      // 12 KB: layers 1..2 matrices
    __shared__ float wlo[64], whi[64];
    __shared__ float csx[16 * 12], snx[16 * 12];     // trig for 16 samples
    __shared__ float Gs0[96];                        // layer-0 fused gates (persist)
    __shared__ __align__(16) float fct[4][48][2];    // per-wave factor tables
    float* Gs = (float*)&Sst[0][0];  // 288-float overlay, dead after W-build

    const int t = threadIdx.x, blk = blockIdx.x;

    // ---- Phase 1: gates t<36; wlo/whi t<64; trig t in [64,256) ----
    if (t < 36) {   // fused 2x2 gates G = RY(p2)RZ(p1)RY(p0)  (R4-verified)
        float p0 = params[t * 3 + 0], p1 = params[t * 3 + 1], p2 = params[t * 3 + 2];
        float c0 = cosf(0.5f * p0), s0 = sinf(0.5f * p0);
        float ch = cosf(0.5f * p1), sh = sinf(0.5f * p1);
        float c2 = cosf(0.5f * p2), s2 = sinf(0.5f * p2);
        float pr_ = ch, pi = -sh, qr = ch, qi = sh;
        float A = c2 * c0, Bc = s2 * s0, Cc = c2 * s0, D = s2 * c0;
        float* g = &Gs[t * 8];
        g[0] = A * pr_ - Bc * qr;  g[1] = A * pi - Bc * qi;
        g[2] = -Cc * pr_ - D * qr; g[3] = -Cc * pi - D * qi;
        g[4] = D * pr_ + Cc * qr;  g[5] = D * pi + Cc * qi;
        g[6] = -Bc * pr_ + A * qr; g[7] = -Bc * pi + A * qi;
    }
    if (t < 64) {                  // wlo (bits<->wires 11..6) AND whi (wires 5..0)
        int v = t; float s = 0.f, s2 = 0.f;
#pragma unroll
        for (int be = 0; be < 6; ++be) {
            s  += ((v >> be) & 1) ? -head_w[11 - be] : head_w[11 - be];
            s2 += ((v >> be) & 1) ? -head_w[5 - be]  : head_w[5 - be];
        }
        wlo[v] = s; whi[v] = s2;
    }
    if (t >= 64) {                 // RX trig for this block's 16 samples
        int idx = t - 64;          // 0..191
        int slot = idx / 12, w = idx - slot * 12;
        int smp = (slot >> 2) * (GRID * 4) + blk * 4 + (slot & 3);
        if (smp < Btot) {
            float xv = 0.5f * x[smp * NQ + w];
            csx[slot * 12 + w] = cosf(xv);
            snx[slot * 12 + w] = sinf(xv);
        }
    }
    __syncthreads();

    // ---- Phase 2: W build for layers 1..2 + persist layer-0 gates ----
    if (t < 96) Gs0[t] = Gs[t];    // layer-0 gates, wires 0..11
#pragma unroll
    for (int i = 0; i < 24; ++i) {
        int e = i * 256 + t;       // 0..6143
        int s = (e >> 10) + 3;     // skip the 3 layer-0 matrices
        int idx = e & 1023;
        int n = idx >> 5, k = idx & 31;
        int rp = n >> 4, tp = n & 15, rr = k >> 4, tt = k & 15;
        int l = s / 3, g = s - 3 * l;
        float ur = 1.f, ui = 0.f;
#pragma unroll
        for (int jj = 0; jj < 4; ++jj) {
            int wire = 11 - (4 * g + jj);
            const float* gp = &Gs[(l * 12 + wire) * 8];
            int rb = (tp >> jj) & 1, cb = (tt >> jj) & 1;
            float gr = gp[(rb * 2 + cb) * 2], gi = gp[(rb * 2 + cb) * 2 + 1];
            float nr = ur * gr - ui * gi;
            float ni = ur * gi + ui * gr;
            ur = nr; ui = ni;
        }
        float val = (rp == 0) ? ((rr == 0) ? ur : -ui)
                              : ((rr == 0) ? ui : ur);
        Wl[swzw(e)] = (_Float16)val;
    }
    __syncthreads();
    // ======== NO MORE BARRIERS BELOW THIS POINT ========

    const int wv = t >> 6, lane = t & 63, u = t & 15, q = (t >> 4) & 3;
    _Float16* Ss = &Sst[wv][0];
    const int wbs = swzw(u * 32 + q * 8);
    // scatter/readout lane-constants (wave-role-independent)
    const int s4 = (u ^ (u >> 1) ^ (u >> 2) ^ (u >> 3)) & 15;
    const int P4 = s4 & 1, q0 = q & 1, q1 = q >> 1;
    const int j7 = q1 ^ P4, j6 = q0 ^ q1 ^ P4;
    const float whiv = whi[s4 * 4 + j7 * 2 + j6];
    const f4 Z = {0.f, 0.f, 0.f, 0.f};

#define ST16(off_, va_, vb_) {                                               \
    union { unsigned u[4]; h8 v; } w_;                                       \
    w_.u[0] = pk2((va_).x, (va_).y); w_.u[1] = pk2((va_).z, (va_).w);        \
    w_.u[2] = pk2((vb_).x, (vb_).y); w_.u[3] = pk2((vb_).z, (vb_).w);        \
    *(h8*)&Ss[off_] = w_.v; }

// CNOT scatter of reg-component r_ (r0_,r1_ = bits of r_), for role wvx.
#define PSTX(CMP_, r0_, r1_) {                                               \
    int j5_ = (r1_) ^ j6, j4_ = ((r0_) ^ (r1_)) ^ j6;                        \
    int j3_ = wv1 ^ j4_, j2_ = wv0 ^ wv1 ^ j4_;                              \
    int m0_ = s4 * 16 + j7 * 8 + j6 * 4 + j5_ * 2 + j4_;                     \
    int Eo_ = swzf(m0_ * 32 + j3_ * 8 + j2_ * 4);                            \
    bool pw_ = ((wv0 ^ wv1 ^ j4_) != 0);                                     \
    { float v0=eRA[0].CMP_, v1=eRA[1].CMP_, v2=eRA[2].CMP_, v3=eRA[3].CMP_;  \
      float a0_=pw_?v2:v0, a1_=pw_?v3:v1, a2_=pw_?v1:v3, a3_=pw_?v0:v2;      \
      union { unsigned u[2]; h4 v; } w_;                                     \
      w_.u[0]=pk2(a0_,a1_); w_.u[1]=pk2(a2_,a3_);                            \
      *(h4*)&Ss[Eo_] = w_.v; }                                               \
    { float v0=eIA[0].CMP_, v1=eIA[1].CMP_, v2=eIA[2].CMP_, v3=eIA[3].CMP_;  \
      float a0_=pw_?v2:v0, a1_=pw_?v3:v1, a2_=pw_?v1:v3, a3_=pw_?v0:v2;      \
      union { unsigned u[2]; h4 v; } w_;                                     \
      w_.u[0]=pk2(a0_,a1_); w_.u[1]=pk2(a2_,a3_);                            \
      *(h4*)&Ss[Eo_ ^ 16] = w_.v; } }

#define RDX(CMP_, dr_) {                                                     \
    int b_ = wloB_ ^ (dr_);                                                  \
    float w0_ = whiv + wlo[b_],     w1_ = whiv + wlo[b_ ^ 1];                \
    float w2_ = whiv + wlo[b_ ^ 3], w3_ = whiv + wlo[b_ ^ 2];                \
    racc = fmaf(fmaf(eRA[0].CMP_, eRA[0].CMP_, eIA[0].CMP_*eIA[0].CMP_), w0_, racc); \
    racc = fmaf(fmaf(eRA[1].CMP_, eRA[1].CMP_, eIA[1].CMP_*eIA[1].CMP_), w1_, racc); \
    racc = fmaf(fmaf(eRA[2].CMP_, eRA[2].CMP_, eIA[2].CMP_*eIA[2].CMP_), w2_, racc); \
    racc = fmaf(fmaf(eRA[3].CMP_, eRA[3].CMP_, eIA[3].CMP_*eIA[3].CMP_), w3_, racc); }

    // ---- sample loop: wave-private, no block sync ----
#pragma unroll 1
    for (int pr = 0; pr < 4; ++pr) {
        const int smp = (pr * GRID + blk) * 4 + wv;
        if (smp >= Btot) continue;

        // ---- factor table (lanes 0..47 of this wave; wave-local) ----
        if (lane < 48) {
            int k_ = lane;
            int grp = k_ >> 4, h = k_ & 15;
            int wbase = (grp == 0) ? 3 : (grp == 1) ? 7 : 11;
            const int slot = pr * 4 + wv;
            const float* cs_ = &csx[slot * 12];
            const float* sn_ = &snx[slot * 12];
            float ur = 1.f, ui = 0.f;
#pragma unroll
            for (int jj = 0; jj < 4; ++jj) {
                int w = wbase - jj;
                int bit = (h >> jj) & 1;
                const float* g = &Gs0[w * 8];
                float c = cs_[w], sn = sn_[w];
                float tr, ti;
                if (bit == 0) { tr = g[0] * c + g[3] * sn; ti = g[1] * c - g[2] * sn; }
                else          { tr = g[4] * c + g[7] * sn; ti = g[5] * c - g[6] * sn; }
                float nr = ur * tr - ui * ti, ni = ur * ti + ui * tr;
                ur = nr; ui = ni;
            }
            fct[wv][k_][0] = ur; fct[wv][k_][1] = ui;
        }
        // (lgkmcnt orders fct writes before reads below; same wave)

        // ---- materialize layer-1 input: rows m = mx*64+lane, all 4 mx ----
#pragma unroll
        for (int mx = 0; mx < 4; ++mx) {
            const int m = mx * 64 + lane;
            const int iu_ = (m ^ (m >> 1)) & 0xFF;
            const int aI_ = iu_ >> 4, bI_ = 16 + (iu_ & 15);
            const int flip_ = (m & 1) << 3;
            float ar = fct[wv][aI_][0], ai = fct[wv][aI_][1];
            float br = fct[wv][bI_][0], bi = fct[wv][bI_][1];
            float abr = ar * br - ai * bi, abi = ar * bi + ai * br;
            float cr[16], ci[16];
#pragma unroll
            for (int k2 = 0; k2 < 16; k2 += 2) {
                f4 v = *(const f4*)&fct[wv][32 + (k2 ^ flip_)][0];
                cr[k2] = v.x; ci[k2] = v.y; cr[k2 + 1] = v.z; ci[k2 + 1] = v.w;
            }
            float vr_[16], vi_[16];
#pragma unroll
            for (int tau = 0; tau < 16; ++tau) {
                const int cidx = tau ^ (tau >> 1);
                vr_[tau] = abr * cr[cidx] - abi * ci[cidx];
                vi_[tau] = abr * ci[cidx] + abi * cr[cidx];
            }
            union { unsigned u[4]; h8 v; } R0_, R1_, I0_, I1_;
#pragma unroll
            for (int k = 0; k < 4; ++k) {
                R0_.u[k] = pk2(vr_[2 * k],     vr_[2 * k + 1]);
                R1_.u[k] = pk2(vr_[8 + 2 * k], vr_[8 + 2 * k + 1]);
                I0_.u[k] = pk2(vi_[2 * k],     vi_[2 * k + 1]);
                I1_.u[k] = pk2(vi_[8 + 2 * k], vi_[8 + 2 * k + 1]);
            }
            const int off0 = m * 32;
            *(h8*)&Ss[swzf(off0)]      = R0_.v;
            *(h8*)&Ss[swzf(off0 + 8)]  = R1_.v;
            *(h8*)&Ss[swzf(off0 + 16)] = I0_.v;
            *(h8*)&Ss[swzf(off0 + 24)] = I1_.v;
        }

        float racc = 0.f;
#pragma unroll
        for (int l = 1; l < NL; ++l) {
            // ---- g0: all 4 roles; in-place per 4KB chunk (read->MFMA->write) ----
            {
                const int sW = ((l - 1) * 3 + 0) * 1024;
                h8 bf0 = *(const h8*)&Wl[sW + wbs];
                h8 bf1 = *(const h8*)&Wl[sW + 512 + wbs];
#pragma unroll
                for (int wvx = 0; wvx < 4; ++wvx) {
                    h8 aA[4];
#pragma unroll
                    for (int mb = 0; mb < 4; ++mb) {
                        int m_ = wvx * 64 + (u >> 2) * 16 + mb * 4 + (u & 3);
                        aA[mb] = *(const h8*)&Ss[swzf(m_ * 32 + q * 8)];
                    }
                    f4 cR[4], cI[4];
#pragma unroll
                    for (int mb = 0; mb < 4; ++mb) {
                        cR[mb] = MFMA(aA[mb], bf0, Z, 0, 0, 0);
                        cI[mb] = MFMA(aA[mb], bf1, Z, 0, 0, 0);
                    }
                    const int tx = wvx * 64 + lane;
                    const int sb_ = (tx * 32) ^ (((tx ^ (tx >> 4)) & 7) << 3);
                    ST16(sb_,      cR[0], cR[1]) ST16(sb_ ^ 8,  cR[2], cR[3])
                    ST16(sb_ ^ 16, cI[0], cI[1]) ST16(sb_ ^ 24, cI[2], cI[3])
                }
            }
            // ---- g1+g2: stage ALL 16 A-frags first (closes scatter hazard) ----
            {
                const int sW1 = ((l - 1) * 3 + 1) * 1024, sW2 = ((l - 1) * 3 + 2) * 1024;
                h8 bg0 = *(const h8*)&Wl[sW1 + wbs];
                h8 bg1 = *(const h8*)&Wl[sW1 + 512 + wbs];
                h8 bh0 = *(const h8*)&Wl[sW2 + wbs];
                h8 bh1 = *(const h8*)&Wl[sW2 + 512 + wbs];
                h8 gA[16];
#pragma unroll
                for (int wvx = 0; wvx < 4; ++wvx)
#pragma unroll
                    for (int mb = 0; mb < 4; ++mb) {
                        int m1 = ((lane >> 2) & 3) * 64 + (lane & 3) * 16 + wvx * 4 + mb;
                        gA[wvx * 4 + mb] = *(const h8*)&Ss[swz1(m1 * 32 + q * 8)];
                    }
#pragma unroll
                for (int wvx = 0; wvx < 4; ++wvx) {
                    f4 dR[4], dI[4]; h8 t2[4];
#pragma unroll
                    for (int mb = 0; mb < 4; ++mb) {
                        dR[mb] = MFMA(gA[wvx * 4 + mb], bg0, Z, 0, 0, 0);
                        dI[mb] = MFMA(gA[wvx * 4 + mb], bg1, Z, 0, 0, 0);
                    }
#pragma unroll
                    for (int mb = 0; mb < 4; ++mb) t2[mb] = xition(dR[mb], dI[mb]);
                    f4 eRA[4], eIA[4];
#pragma unroll
                    for (int mb = 0; mb < 4; ++mb) {
                        eRA[mb] = MFMA(t2[mb], bh0, Z, 0, 0, 0);
                        eIA[mb] = MFMA(t2[mb], bh1, Z, 0, 0, 0);
                    }
                    const int wv0 = wvx & 1, wv1 = wvx >> 1;
                    if (l < NL - 1) {
                        PSTX(x, 0, 0) PSTX(y, 1, 0) PSTX(z, 0, 1) PSTX(w, 1, 1)
                    } else {
                        const int Pw0_ = wv0 ^ wv1 ^ j6;
                        const int wloB_ = j6 * 48 + (wv1 ^ j6) * 8 +
                                          (wv0 ^ wv1 ^ j6) * 4 + Pw0_ * 3;
                        RDX(x, 0) RDX(y, 31) RDX(z, 63) RDX(w, 32)
                    }
                }
            }
        }
        // ---- wave-local reduce + store (no wred, no barrier) ----
#pragma unroll
        for (int o = 32; o >= 1; o >>= 1)
            racc += __shfl_xor(racc, o, 64);
        if (lane == 0) out[smp] = head_b[0] + racc;
    }
}

extern "C" void kernel_launch(void* const* d_in, const int* in_sizes, int n_in,
                              void* d_out, int out_size, void* d_ws, size_t ws_size,
                              hipStream_t stream) {
    const float* x = (const float*)d_in[0];
    const float* params = (const float*)d_in[1];
    const float* head_w = (const float*)d_in[2];
    const float* head_b = (const float*)d_in[3];
    float* out = (float*)d_out;
    int B = in_sizes[0] / NQ;

    hipLaunchKernelGGL(qsim_kernel, dim3(GRID), dim3(NTH), 0, stream,
                       x, params, head_w, head_b, out, B);
}

// Round 16
// 102.927 us; speedup vs baseline: 1.1436x; 1.1436x over previous
//
#include <hip/hip_runtime.h>
#include <math.h>

#define NQ 12
#define NTH 256
#define NL 3
#define GRID 1024  // 1 sample/block, ~31 KB LDS -> 4 blocks/CU; 8 samples/block

typedef _Float16 h8 __attribute__((ext_vector_type(8)));
typedef _Float16 h4 __attribute__((ext_vector_type(4)));
typedef float f4 __attribute__((ext_vector_type(4)));

#define MFMA __builtin_amdgcn_mfma_f32_16x16x32_f16

// R30 = R25 VERBATIM (session best: 55.4us dispatch / 103.07us total).
// R28/R29's two-kernel split failed correctness twice with identical
// table-corruption symptoms despite index-identical math (d_ws AND module
// globals) -> multi-kernel launch contract is the suspect; gain didn't
// justify further rounds. R25 structure = single kernel, 1 sample/block:
//  * layer-0 telescoped (tensor-product materialization, R16)
//  * in-register g1->g2 transition via permlane swaps (R15)
//  * barrier diet: 6/sample (R19-verified elisions)
//  * v_cvt_pkrtz packing (R21), f4 fct reads + hoisted readout weights (R25)
// Ledger R19-R27: barriers -44%, VALU -15%, DS -40%, occupancy 18->35%,
// wave-per-sample, 8-wave blocks -- all <=+-2% or spill-regressions.
// All pipes ~50% => latency-bound structural floor of this decomposition.
//
// Bit bookkeeping (state index i[11:0], wire w <-> bit 11-w):
//  L0 (LDS): off = i[11:4]*32 + reim*16 + i[3:0], swzf
//  g0 A: elem=i[2:0], q=(reim,i[3]), row u=(i[9:8],i[5:4]), mb=i[7:6], wave=i[11:10]
//  L1 (LDS): off = m1*32 + reim*16 + i[7:4], m1=(i[11:10],i[9:8],i[3:0]), swz1
//  g1 A: elem=i[6:4], q=(reim,i[7]), row=i[11:8], mb=i[1:0], wave=i[3:2]
//  in-reg transition -> g2 A: elem=i[10:8], q=(reim,i[11]), row=i[7:4], mb=i[1:0]
//  C(g2): col=i[11:8](lane3:0), l5:4=i[7:6], reg=i[5:4], mb=i[1:0], wave=i[3:2]
//  CNOT scatter: dest j = sfx(i) (suffix parity), h4-contiguous in j[1:0]<->mb.

__device__ __forceinline__ int sfx(int v) {
    v ^= v >> 1; v ^= v >> 2; v ^= v >> 4; v ^= v >> 8;
    return v;
}
__device__ __forceinline__ int swzf(int off) {   // L0 swizzle (R6-verified)
    return off ^ (((((off >> 6) ^ (off >> 9)) & 7)) << 3);
}
__device__ __forceinline__ int swz1(int off) {   // L1 swizzle (rank-3 bank classes both sides)
    return off ^ ((((off >> 5) ^ (off >> 9)) & 7) << 3);
}
__device__ __forceinline__ int swzw(int off) {   // W-buffer swizzle (R7-verified)
    return off ^ (((off >> 6) & 7) << 3);
}

// f32 pair -> packed 2xf16 dword via v_cvt_pkrtz_f16_f32 (lo in low half)
__device__ __forceinline__ unsigned pk2(float lo, float hi) {
    auto t_ = __builtin_amdgcn_cvt_pkrtz(lo, hi);   // __fp16x2
    unsigned r_; __builtin_memcpy(&r_, &t_, 4); return r_;
}

// C(g1) fragment (4 re regs + 4 im regs) -> A(g2) h8 fragment, in-wave.
__device__ __forceinline__ h8 xition(f4 re, f4 im) {
    unsigned a0 = pk2(re.x, re.y), a1 = pk2(re.z, re.w);
    unsigned b0 = pk2(im.x, im.y), b1 = pk2(im.z, im.w);
    asm("v_permlane32_swap_b32 %0, %1" : "+v"(a0), "+v"(b0));
    asm("v_permlane16_swap_b32 %0, %1" : "+v"(a0), "+v"(b0));
    asm("v_permlane32_swap_b32 %0, %1" : "+v"(a1), "+v"(b1));
    asm("v_permlane16_swap_b32 %0, %1" : "+v"(a1), "+v"(b1));
    union { unsigned u[4]; h8 v; } r_;
    r_.u[0] = a0; r_.u[1] = a1; r_.u[2] = b0; r_.u[3] = b1;
    return r_.v;
}

__global__ void __launch_bounds__(NTH, 4)
qsim_kernel(const float* __restrict__ x,
            const float* __restrict__ params,
            const float* __restrict__ head_w,
            const float* __restrict__ head_b,
            float* __restrict__ out, int Btot) {
    __shared__ __align__(16) _Float16 Sst[8192];   // 16 KB: one sample's state
    __shared__ __align__(16) _Float16 Wl[6144];    // 12 KB: layers 1..2 matrices
    __shared__ float wlo[64], whi[64];
    __shared__ float csx[8 * 12], snx[8 * 12];     // trig for up to 8 samples
    __shared__ float Gs0[96];                      // layer-0 fused gates (persist)
    __shared__ __align__(16) float fct[48][2];     // per-sample factor tables A|B|C
    __shared__ float wred[4];
    float* Gs = (float*)Sst;   // 288-float overlay, dead after W-build

    const int t = threadIdx.x, blk = blockIdx.x;

    // ---- Phase 1: lane ranges (gates t<36; wlo/whi t<64; trig t in [64,160)) ----
    if (t < 36) {   // fused 2x2 gates G = RY(p2)RZ(p1)RY(p0)  (R4-verified)
        float p0 = params[t * 3 + 0], p1 = params[t * 3 + 1], p2 = params[t * 3 + 2];
        float c0 = cosf(0.5f * p0), s0 = sinf(0.5f * p0);
        float ch = cosf(0.5f * p1), sh = sinf(0.5f * p1);
        float c2 = cosf(0.5f * p2), s2 = sinf(0.5f * p2);
        float pr_ = ch, pi = -sh, qr = ch, qi = sh;
        float A = c2 * c0, Bc = s2 * s0, Cc = c2 * s0, D = s2 * c0;
        float* g = &Gs[t * 8];
        g[0] = A * pr_ - Bc * qr;  g[1] = A * pi - Bc * qi;
        g[2] = -Cc * pr_ - D * qr; g[3] = -Cc * pi - D * qi;
        g[4] = D * pr_ + Cc * qr;  g[5] = D * pi + Cc * qi;
        g[6] = -Bc * pr_ + A * qr; g[7] = -Bc * pi + A * qi;
    }
    if (t < 64) {                  // wlo (bits<->wires 11..6) AND whi (wires 5..0)
        int v = t; float s = 0.f, s2 = 0.f;
#pragma unroll
        for (int be = 0; be < 6; ++be) {
            s  += ((v >> be) & 1) ? -head_w[11 - be] : head_w[11 - be];
            s2 += ((v >> be) & 1) ? -head_w[5 - be]  : head_w[5 - be];
        }
        wlo[v] = s; whi[v] = s2;
    }
    if (t >= 64 && t < 160) {      // RX trig for this block's <=8 samples
        int idx = t - 64;          // 0..95
        int pr = idx / 12, w = idx - pr * 12;
        int smp = blk + pr * GRID;
        if (smp < Btot) {
            float xv = 0.5f * x[smp * NQ + w];
            csx[pr * 12 + w] = cosf(xv);
            snx[pr * 12 + w] = sinf(xv);
        }
    }
    __syncthreads();

    // ---- Phase 2: W build for layers 1..2 + persist layer-0 gates ----
    if (t < 96) Gs0[t] = Gs[t];    // layer-0 gates, wires 0..11
#pragma unroll
    for (int i = 0; i < 24; ++i) {
        int e = i * 256 + t;       // 0..6143
        int s = (e >> 10) + 3;     // skip the 3 layer-0 matrices
        int idx = e & 1023;
        int n = idx >> 5, k = idx & 31;
        int rp = n >> 4, tp = n & 15, rr = k >> 4, tt = k & 15;
        int l = s / 3, g = s - 3 * l;
        float ur = 1.f, ui = 0.f;
#pragma unroll
        for (int jj = 0; jj < 4; ++jj) {
            int wire = 11 - (4 * g + jj);
            const float* gp = &Gs[(l * 12 + wire) * 8];
            int rb = (tp >> jj) & 1, cb = (tt >> jj) & 1;
            float gr = gp[(rb * 2 + cb) * 2], gi = gp[(rb * 2 + cb) * 2 + 1];
            float nr = ur * gr - ui * gi;
            float ni = ur * gi + ui * gr;
            ur = nr; ui = ni;
        }
        float val = (rp == 0) ? ((rr == 0) ? ur : -ui)
                              : ((rr == 0) ? ui : ur);
        Wl[swzw(e)] = (_Float16)val;
    }
    __syncthreads();

    // ---- per-lane constants ----
    const int wv = t >> 6, u = t & 15, q = (t >> 4) & 3;
    const int wbs = swzw(u * 32 + q * 8);
    int g0b[4], g1b[4];
#pragma unroll
    for (int mb = 0; mb < 4; ++mb) {
        int m_ = wv * 64 + (u >> 2) * 16 + mb * 4 + (u & 3);
        g0b[mb] = swzf(m_ * 32 + q * 8);
        int l_ = t & 63;
        int m1 = ((l_ >> 2) & 3) * 64 + (l_ & 3) * 16 + wv * 4 + mb;
        g1b[mb] = swz1(m1 * 32 + q * 8);
    }
    const int sb = (t * 32) ^ (((t ^ (t >> 4)) & 7) << 3);  // swz1(t*32)

    // CNOT-scatter (dest j = sfx(i)) + readout constants
    const int s4 = (u ^ (u >> 1) ^ (u >> 2) ^ (u >> 3)) & 15;
    const int P4 = s4 & 1, q0 = q & 1, q1 = q >> 1;
    const int j7 = q1 ^ P4, j6 = q0 ^ q1 ^ P4;
    const int wv0 = wv & 1, wv1 = wv >> 1;
    int Eo[4], PwR[4];
#pragma unroll
    for (int r = 0; r < 4; ++r) {
        int r0 = r & 1, r1 = r >> 1;
        int j5 = r1 ^ j6, j4 = (r0 ^ r1) ^ j6;
        int j3 = wv1 ^ j4, j2 = wv0 ^ wv1 ^ j4;
        int m0 = s4 * 16 + j7 * 8 + j6 * 4 + j5 * 2 + j4;
        Eo[r]  = swzf(m0 * 32 + j3 * 8 + j2 * 4);
        PwR[r] = (wv0 ^ wv1 ^ j4);
    }
    const int Pw0 = wv0 ^ wv1 ^ j6;
    const int wloB = j6 * 48 + (wv1 ^ j6) * 8 + (wv0 ^ wv1 ^ j6) * 4 + Pw0 * 3;
    const float whiv = whi[s4 * 4 + j7 * 2 + j6];
    const f4 Z = {0.f, 0.f, 0.f, 0.f};

    // readout weights are loop-invariant -> hoist all 16 into VGPRs.
    // dr mapping per RD1 component: x->0, y->31, z->63, w->32; deltas 1,3,2.
    const float Wa0 = whiv + wlo[wloB],      Wa1 = whiv + wlo[wloB ^ 1];
    const float Wa2 = whiv + wlo[wloB ^ 3],  Wa3 = whiv + wlo[wloB ^ 2];
    const float Wb0 = whiv + wlo[wloB ^ 31], Wb1 = whiv + wlo[wloB ^ 30];
    const float Wb2 = whiv + wlo[wloB ^ 28], Wb3 = whiv + wlo[wloB ^ 29];
    const float Wc0 = whiv + wlo[wloB ^ 63], Wc1 = whiv + wlo[wloB ^ 62];
    const float Wc2 = whiv + wlo[wloB ^ 60], Wc3 = whiv + wlo[wloB ^ 61];
    const float Wd0 = whiv + wlo[wloB ^ 32], Wd1 = whiv + wlo[wloB ^ 33];
    const float Wd2 = whiv + wlo[wloB ^ 35], Wd3 = whiv + wlo[wloB ^ 34];

    // layer-1 init constants: i = invsfx(j), j[11:4] = t
    const int iu = (t ^ (t >> 1)) & 0xFF;   // i[11:4]
    const int aI = iu >> 4;                 // A16 index i[11:8]
    const int bI = 16 + (iu & 15);          // B16 index i[7:4]
    const int flip = (t & 1) << 3;          // i3 = tau3 ^ j4

#define ST16(off_, va_, vb_) {                                               \
    union { unsigned u[4]; h8 v; } w_;                                       \
    w_.u[0] = pk2((va_).x, (va_).y); w_.u[1] = pk2((va_).z, (va_).w);        \
    w_.u[2] = pk2((vb_).x, (vb_).y); w_.u[3] = pk2((vb_).z, (vb_).w);        \
    *(h8*)&Sst[off_] = w_.v; }

// CNOT scatter of one reg-component r_ (both reims, one sample).
// slot order: Pw=0 -> (v0,v1,v3,v2); Pw=1 -> (v2,v3,v1,v0)
#define PST1(CMP_, r_) {                                                     \
    bool pw_ = PwR[r_] != 0;                                                 \
    { float v0=eRA[0].CMP_, v1=eRA[1].CMP_, v2=eRA[2].CMP_, v3=eRA[3].CMP_;  \
      float a0_=pw_?v2:v0, a1_=pw_?v3:v1, a2_=pw_?v1:v3, a3_=pw_?v0:v2;      \
      union { unsigned u[2]; h4 v; } w_;                                     \
      w_.u[0]=pk2(a0_,a1_); w_.u[1]=pk2(a2_,a3_);                            \
      *(h4*)&Sst[Eo[r_]] = w_.v; }                                           \
    { float v0=eIA[0].CMP_, v1=eIA[1].CMP_, v2=eIA[2].CMP_, v3=eIA[3].CMP_;  \
      float a0_=pw_?v2:v0, a1_=pw_?v3:v1, a2_=pw_?v1:v3, a3_=pw_?v0:v2;      \
      union { unsigned u[2]; h4 v; } w_;                                     \
      w_.u[0]=pk2(a0_,a1_); w_.u[1]=pk2(a2_,a3_);                            \
      *(h4*)&Sst[Eo[r_] ^ 16] = w_.v; } }

#define RD1(CMP_, W0_, W1_, W2_, W3_) {                                      \
    racc0 = fmaf(fmaf(eRA[0].CMP_, eRA[0].CMP_, eIA[0].CMP_*eIA[0].CMP_), W0_, racc0); \
    racc0 = fmaf(fmaf(eRA[1].CMP_, eRA[1].CMP_, eIA[1].CMP_*eIA[1].CMP_), W1_, racc0); \
    racc0 = fmaf(fmaf(eRA[2].CMP_, eRA[2].CMP_, eIA[2].CMP_*eIA[2].CMP_), W2_, racc0); \
    racc0 = fmaf(fmaf(eRA[3].CMP_, eRA[3].CMP_, eIA[3].CMP_*eIA[3].CMP_), W3_, racc0); }

    // ---- sample loop (grid-stride over 8192 samples, 8 per block even) ----
#pragma unroll 1
    for (int pr = 0; ; ++pr) {
        const int smp = blk + pr * GRID;
        if (smp >= Btot) break;

        // ---- factor table: fct[0..15]=A16, [16..31]=B16, [32..47]=C16 ----
        if (t < 48) {
            int k_ = t;
            int grp = k_ >> 4, h = k_ & 15;
            int wbase = (grp == 0) ? 3 : (grp == 1) ? 7 : 11;
            const float* cs_ = &csx[pr * 12];
            const float* sn_ = &snx[pr * 12];
            float ur = 1.f, ui = 0.f;
#pragma unroll
            for (int jj = 0; jj < 4; ++jj) {
                int w = wbase - jj;
                int bit = (h >> jj) & 1;
                const float* g = &Gs0[w * 8];
                float c = cs_[w], sn = sn_[w];
                float tr, ti;
                if (bit == 0) { tr = g[0] * c + g[3] * sn; ti = g[1] * c - g[2] * sn; }
                else          { tr = g[4] * c + g[7] * sn; ti = g[5] * c - g[6] * sn; }
                float nr = ur * tr - ui * ti, ni = ur * ti + ui * tr;
                ur = nr; ui = ni;
            }
            fct[k_][0] = ur; fct[k_][1] = ui;
        }
        __syncthreads();                              // (B1) table ready

        // ---- materialize layer-1 input: state1[j] = A.B.C at i=invsfx(j) ----
        // (writes rows m=t: wave-local; no barrier needed before g0 reads)
        {
            float ar = fct[aI][0], ai = fct[aI][1];
            float br = fct[bI][0], bi = fct[bI][1];
            float abr = ar * br - ai * bi, abi = ar * bi + ai * br;
            float cr[16], ci[16];
#pragma unroll
            for (int k2 = 0; k2 < 16; k2 += 2) {      // f4: flip preserves pair adjacency
                f4 v = *(const f4*)&fct[32 + (k2 ^ flip)][0];
                cr[k2] = v.x; ci[k2] = v.y; cr[k2 + 1] = v.z; ci[k2 + 1] = v.w;
            }
            float vr_[16], vi_[16];
#pragma unroll
            for (int tau = 0; tau < 16; ++tau) {
                const int cidx = tau ^ (tau >> 1);    // compile-time
                vr_[tau] = abr * cr[cidx] - abi * ci[cidx];
                vi_[tau] = abr * ci[cidx] + abi * cr[cidx];
            }
            union { unsigned u[4]; h8 v; } R0_, R1_, I0_, I1_;
#pragma unroll
            for (int k = 0; k < 4; ++k) {
                R0_.u[k] = pk2(vr_[2 * k],     vr_[2 * k + 1]);
                R1_.u[k] = pk2(vr_[8 + 2 * k], vr_[8 + 2 * k + 1]);
                I0_.u[k] = pk2(vi_[2 * k],     vi_[2 * k + 1]);
                I1_.u[k] = pk2(vi_[8 + 2 * k], vi_[8 + 2 * k + 1]);
            }
            const int off0 = t * 32;
            *(h8*)&Sst[swzf(off0)]      = R0_.v;
            *(h8*)&Sst[swzf(off0 + 8)]  = R1_.v;
            *(h8*)&Sst[swzf(off0 + 16)] = I0_.v;
            *(h8*)&Sst[swzf(off0 + 24)] = I1_.v;
        }
        // (B2 elided: g0 reads below are wave-local to the rows just written)

        float racc0 = 0.f;
#pragma unroll
        for (int l = 1; l < NL; ++l) {
            // ---- g0: tau=i[3:0], then store to L1 (all wave-local; no (b)) ----
            {
                const int sW = ((l - 1) * 3 + 0) * 1024;
                h8 bf0 = *(const h8*)&Wl[sW + wbs];
                h8 bf1 = *(const h8*)&Wl[sW + 512 + wbs];
                h8 aA[4];
#pragma unroll
                for (int mb = 0; mb < 4; ++mb)
                    aA[mb] = *(const h8*)&Sst[g0b[mb]];
                f4 cR[4], cI[4];
#pragma unroll
                for (int mb = 0; mb < 4; ++mb) {
                    cR[mb] = MFMA(aA[mb], bf0, Z, 0, 0, 0);
                    cI[mb] = MFMA(aA[mb], bf1, Z, 0, 0, 0);
                }
                ST16(sb,      cR[0], cR[1]) ST16(sb ^ 8,  cR[2], cR[3])
                ST16(sb ^ 16, cI[0], cI[1]) ST16(sb ^ 24, cI[2], cI[3])
                __syncthreads();                      // (c) L1 ready
            }
            // ---- g1 (LDS read) -> in-reg transition -> g2 (register A) ----
            {
                const int sW1 = ((l - 1) * 3 + 1) * 1024, sW2 = ((l - 1) * 3 + 2) * 1024;
                h8 bg0 = *(const h8*)&Wl[sW1 + wbs];
                h8 bg1 = *(const h8*)&Wl[sW1 + 512 + wbs];
                h8 bh0 = *(const h8*)&Wl[sW2 + wbs];
                h8 bh1 = *(const h8*)&Wl[sW2 + 512 + wbs];
                h8 gA[4];
#pragma unroll
                for (int mb = 0; mb < 4; ++mb)
                    gA[mb] = *(const h8*)&Sst[g1b[mb]];
                if (l < NL - 1) __syncthreads();      // (d) g1 reads done; scatter OK
                f4 eRA[4], eIA[4];
                {
                    f4 dR[4], dI[4]; h8 t2[4];
#pragma unroll
                    for (int mb = 0; mb < 4; ++mb) {
                        dR[mb] = MFMA(gA[mb], bg0, Z, 0, 0, 0);
                        dI[mb] = MFMA(gA[mb], bg1, Z, 0, 0, 0);
                    }
#pragma unroll
                    for (int mb = 0; mb < 4; ++mb) t2[mb] = xition(dR[mb], dI[mb]);
#pragma unroll
                    for (int mb = 0; mb < 4; ++mb) {
                        eRA[mb] = MFMA(t2[mb], bh0, Z, 0, 0, 0);
                        eIA[mb] = MFMA(t2[mb], bh1, Z, 0, 0, 0);
                    }
                }
                if (l < NL - 1) {
                    PST1(x, 0) PST1(y, 1) PST1(z, 2) PST1(w, 3)
                    __syncthreads();                  // (e) L0' ready for next layer
                } else {
                    RD1(x, Wa0, Wa1, Wa2, Wa3)
                    RD1(y, Wb0, Wb1, Wb2, Wb3)
                    RD1(z, Wc0, Wc1, Wc2, Wc3)
                    RD1(w, Wd0, Wd1, Wd2, Wd3)
                }
            }
        }
#pragma unroll
        for (int o = 32; o >= 1; o >>= 1)
            racc0 += __shfl_xor(racc0, o, 64);
        if ((t & 63) == 0) wred[wv] = racc0;
        __syncthreads();                              // wred + orders next iter
        if (t == 0) {
            float r = head_b[0];
#pragma unroll
            for (int i2 = 0; i2 < 4; ++i2) r += wred[i2];
            out[smp] = r;
        }
    }
}

extern "C" void kernel_launch(void* const* d_in, const int* in_sizes, int n_in,
                              void* d_out, int out_size, void* d_ws, size_t ws_size,
                              hipStream_t stream) {
    const float* x = (const float*)d_in[0];
    const float* params = (const float*)d_in[1];
    const float* head_w = (const float*)d_in[2];
    const float* head_b = (const float*)d_in[3];
    float* out = (float*)d_out;
    int B = in_sizes[0] / NQ;

    hipLaunchKernelGGL(qsim_kernel, dim3(GRID), dim3(NTH), 0, stream,
                       x, params, head_w, head_b, out, B);
}